// Round 19
// baseline (657.452 us; speedup 1.0000x reference)
//
#include <hip/hip_runtime.h>

#define T_ 4096
#define B_ 4

typedef unsigned short u16;
typedef __bf16 bf16x8 __attribute__((ext_vector_type(8)));
typedef float f32x4 __attribute__((ext_vector_type(4)));

__device__ inline void splitbf(float v, u16& h, u16& l) {
  __bf16 hb = (__bf16)v;
  float r = v - (float)hb;
  __bf16 lb = (__bf16)r;
  h = __builtin_bit_cast(u16, hb);
  l = __builtin_bit_cast(u16, lb);
}

#define MFMA(a,b,c) __builtin_amdgcn_mfma_f32_16x16x32_bf16((a),(b),(c),0,0,0)

// XCD-aware bijective block swizzle (512 blocks, 8 XCDs, 64 contiguous each)
__device__ inline int xcd_swz(int bid) { return (bid & 7)*64 + (bid >> 3); }

// ---- fused conv1(5x3,pad2)+pool3+relu + conv2(1x12)+pool3+relu, t=4/block
__global__ __launch_bounds__(256) void k_conv12m(
    const float* __restrict__ x, const float* __restrict__ w1,
    const float* __restrict__ b1,
    const u16* __restrict__ wh, const u16* __restrict__ wl,
    const float* __restrict__ b2,
    u16* __restrict__ oh, u16* __restrict__ ol)
{
  __shared__ float sx[8][130];
  __shared__ float w1s[480];
  __shared__ float b1s[32];
  __shared__ __align__(16) char uni[27520];   // 4 regions x 6880 B
  const int tid = threadIdx.x;
  const int t0 = blockIdx.x * 4;
  const int b = blockIdx.y;
  const float* xb = x + (size_t)b*T_*128;
  for (int i = tid; i < 1024; i += 256) {
    int r = i >> 7, c = i & 127;
    int t = t0 - 2 + r;
    sx[r][c] = (t >= 0 && t < T_) ? xb[t*128 + c] : 0.f;
  }
  for (int i = tid; i < 480; i += 256) w1s[i] = w1[i];
  if (tid < 32) b1s[tid] = b1[tid];
  for (int i = tid; i < 160; i += 256) {
    int tt = i / 40, c = i - tt*40;
    u16* shp = (u16*)(uni + tt*6880);
    shp[42*40 + c] = 0;
    shp[1720 + 42*40 + c] = 0;
  }
  __syncthreads();
  {
    const int c1 = tid & 31, tt = (tid >> 5) & 3, hf = tid >> 7;
    u16* shp = (u16*)(uni + tt*6880);
    u16* slp = shp + 1720;
    float w1r[15];
    #pragma unroll
    for (int i = 0; i < 15; i++) w1r[i] = w1s[c1*15 + i];
    float bb1 = b1s[c1];
    const int wp0 = hf*21;
    float win[5][5];
    #pragma unroll
    for (int kh = 0; kh < 5; kh++)
      #pragma unroll
      for (int j = 0; j < 5; j++)
        win[kh][j] = sx[tt+kh][wp0*3 + j];
    for (int wp = wp0; wp < wp0 + 21; wp++) {
      float s0 = 0.f, s1 = 0.f, s2 = 0.f;
      #pragma unroll
      for (int kh = 0; kh < 5; kh++) {
        float wA = w1r[kh*3], wB = w1r[kh*3+1], wC = w1r[kh*3+2];
        s0 += win[kh][0]*wA + win[kh][1]*wB + win[kh][2]*wC;
        s1 += win[kh][1]*wA + win[kh][2]*wB + win[kh][3]*wC;
        s2 += win[kh][2]*wA + win[kh][3]*wB + win[kh][4]*wC;
      }
      float v = fmaxf(fmaxf(fmaxf(s0, s1), s2) + bb1, 0.f);
      u16 hh, ll; splitbf(v, hh, ll);
      int dd = wp*40 + c1;
      shp[dd] = hh; slp[dd] = ll;
      if (wp < wp0 + 20) {
        int c0n = (wp+1)*3;
        #pragma unroll
        for (int kh = 0; kh < 5; kh++) {
          win[kh][0] = win[kh][3];
          win[kh][1] = win[kh][4];
          win[kh][2] = sx[tt+kh][c0n+2];
          win[kh][3] = sx[tt+kh][c0n+3];
          win[kh][4] = sx[tt+kh][c0n+4];
        }
      }
    }
  }
  __syncthreads();
  const int lane = tid & 63;
  const int wid = tid >> 6;
  const int lr = lane & 15;
  const int lk8 = (lane >> 4) * 8;
  const u16* shw = (const u16*)(uni + wid*6880);
  const u16* slw = shw + 1720;
  f32x4 acc[2][4] = {};
  #pragma unroll 3
  for (int kw = 0; kw < 12; kw++) {
    bf16x8 bh[4], bl[4];
    #pragma unroll
    for (int nf = 0; nf < 4; nf++) {
      int go = ((nf*12 + kw) << 9) + (lane << 3);
      bh[nf] = *(const bf16x8*)(wh + go);
      bl[nf] = *(const bf16x8*)(wl + go);
    }
    #pragma unroll
    for (int mf = 0; mf < 2; mf++) {
      int lofs = (mf*16 + lr + kw)*40 + lk8;
      bf16x8 ah = *(const bf16x8*)&shw[lofs];
      bf16x8 al = *(const bf16x8*)&slw[lofs];
      #pragma unroll
      for (int nf = 0; nf < 4; nf++) {
        acc[mf][nf] = MFMA(ah, bl[nf], acc[mf][nf]);
        acc[mf][nf] = MFMA(al, bh[nf], acc[mf][nf]);
        acc[mf][nf] = MFMA(ah, bh[nf], acc[mf][nf]);
      }
    }
  }
  asm volatile("s_waitcnt lgkmcnt(0)" ::: "memory");
  float* dmpw = (float*)(uni + wid*6880);
  const int lg = lane >> 4;
  {
    int t = t0 + wid;
    for (int half = 0; half < 2; half++) {
      #pragma unroll
      for (int mf = 0; mf < 2; mf++)
        #pragma unroll
        for (int r = 0; r < 4; r++) {
          int grow = mf*16 + lg*4 + r;
          int lrow = grow - half*15;
          if (lrow >= 0 && lrow < 15) {
            #pragma unroll
            for (int nf = 0; nf < 4; nf++)
              dmpw[lrow*66 + nf*16 + lr] = acc[mf][nf][r];
          }
        }
      asm volatile("s_waitcnt lgkmcnt(0)" ::: "memory");
      #pragma unroll
      for (int it = 0; it < 5; it++) {
        float v = fmaxf(fmaxf(dmpw[(it*3)*66 + lane], dmpw[(it*3+1)*66 + lane]),
                        dmpw[(it*3+2)*66 + lane]);
        v = fmaxf(v + b2[lane], 0.f);
        u16 hh, ll; splitbf(v, hh, ll);
        size_t o = (size_t)((b*T_ + t)*10 + half*5 + it)*64 + lane;
        oh[o] = hh; ol[o] = ll;
      }
      asm volatile("s_waitcnt lgkmcnt(0)" ::: "memory");
    }
  }
}

// ---------------- conv3 (3x6, pad_h=1) + pool3 + relu via MFMA -------------
__global__ __launch_bounds__(256) void k_conv3m(
    const u16* __restrict__ ih, const u16* __restrict__ il,
    const u16* __restrict__ wh, const u16* __restrict__ wl,
    const float* __restrict__ b3, float* __restrict__ hout)
{
  __shared__ u16 sh[18*720];
  __shared__ u16 sl[18*720];
  __shared__ float dmp[48][132];
  const int tid = threadIdx.x;
  const int t0 = (blockIdx.x & 255) * 16;
  const int b = blockIdx.y;
  for (int i = tid; i < 1440; i += 256) {
    int cg = i & 7;
    int w = (i >> 3) % 10;
    int tt = i / 80;
    int t = t0 - 1 + tt;
    int dd = tt*720 + w*72 + cg*8;
    if (t >= 0 && t < T_) {
      size_t so = (size_t)((b*T_ + t)*10 + w)*64 + cg*8;
      *(ulonglong2*)&sh[dd] = *(const ulonglong2*)&ih[so];
      *(ulonglong2*)&sl[dd] = *(const ulonglong2*)&il[so];
    } else {
      ulonglong2 z; z.x = 0; z.y = 0;
      *(ulonglong2*)&sh[dd] = z;
      *(ulonglong2*)&sl[dd] = z;
    }
  }
  __syncthreads();
  const int lane = tid & 63;
  const int wid = tid >> 6;
  const int lr = lane & 15;
  const int lk8 = (lane >> 4) * 8;
  int tlm[3], wom[3];
  #pragma unroll
  for (int mf = 0; mf < 3; mf++) {
    int r = mf*16 + lr;
    tlm[mf] = r / 3;
    wom[mf] = r - tlm[mf]*3;
  }
  f32x4 acc[3][2] = {};
  #pragma unroll 2
  for (int kh = 0; kh < 3; kh++) {
    #pragma unroll
    for (int kw = 0; kw < 6; kw++) {
      #pragma unroll
      for (int chh = 0; chh < 2; chh++) {
        int s = (kh*6 + kw)*2 + chh;
        int ch = chh*32;
        bf16x8 bh[2], bl[2];
        #pragma unroll
        for (int nfl = 0; nfl < 2; nfl++) {
          int go = (((wid*2 + nfl)*36 + s) << 9) + (lane << 3);
          bh[nfl] = *(const bf16x8*)(wh + go);
          bl[nfl] = *(const bf16x8*)(wl + go);
        }
        #pragma unroll
        for (int mf = 0; mf < 3; mf++) {
          int lofs = (tlm[mf] + kh)*720 + (wom[mf] + kw)*72 + ch + lk8;
          bf16x8 ah = *(const bf16x8*)&sh[lofs];
          bf16x8 al = *(const bf16x8*)&sl[lofs];
          #pragma unroll
          for (int nfl = 0; nfl < 2; nfl++) {
            acc[mf][nfl] = MFMA(ah, bl[nfl], acc[mf][nfl]);
            acc[mf][nfl] = MFMA(al, bh[nfl], acc[mf][nfl]);
            acc[mf][nfl] = MFMA(ah, bh[nfl], acc[mf][nfl]);
          }
        }
      }
    }
  }
  const int lg = lane >> 4;
  #pragma unroll
  for (int mf = 0; mf < 3; mf++)
    #pragma unroll
    for (int r = 0; r < 4; r++) {
      int row = mf*16 + lg*4 + r;
      #pragma unroll
      for (int nfl = 0; nfl < 2; nfl++)
        dmp[row][wid*32 + nfl*16 + lr] = acc[mf][nfl][r];
    }
  __syncthreads();
  for (int i = tid; i < 2048; i += 256) {
    int c3 = i & 127;
    int tt = i >> 7;
    float v = fmaxf(fmaxf(dmp[tt*3][c3], dmp[tt*3+1][c3]), dmp[tt*3+2][c3]);
    v = fmaxf(v + b3[c3], 0.f);
    hout[(size_t)(b*T_ + t0 + tt)*128 + c3] = v;
  }
}

__device__ inline float wave_sum(float v) {
  #pragma unroll
  for (int m = 1; m < 64; m <<= 1) v += __shfl_xor(v, m, 64);
  return v;
}

// ---------------- weight prep (vectorized: 4 elements per thread) ----------
__device__ inline void prep_fr4(const float* __restrict__ src,
                                u16* __restrict__ dh, u16* __restrict__ dl,
                                int K, int N, int matStride, int idx4)
{
  float4 v4 = *(const float4*)&src[idx4];
  float vv[4] = {v4.x, v4.y, v4.z, v4.w};
  #pragma unroll
  for (int j = 0; j < 4; j++) {
    int idx = idx4 + j;
    int mat = idx / (K*N);
    int rem = idx - mat*(K*N);
    int k = rem / N;
    int n = rem - k*N;
    u16 h, l; splitbf(vv[j], h, l);
    int nt = n >> 4, ks = k >> 5, ksub = k & 31;
    size_t o = (size_t)mat*matStride + (size_t)((nt*(K>>5) + ks) << 9)
             + (((ksub >> 3) << 4) + (n & 15))*8 + (ksub & 7);
    dh[o] = h; dl[o] = l;
  }
}

__global__ __launch_bounds__(256) void k_wprep_all(
    const float* __restrict__ Wq, const float* __restrict__ Wk,
    const float* __restrict__ Wv, const float* __restrict__ Wo,
    const float* __restrict__ W1, const float* __restrict__ W2,
    const float* __restrict__ c2w, const float* __restrict__ c3w,
    u16* wqkv_h, u16* wqkv_l, u16* wo_h, u16* wo_l,
    u16* w1t_h, u16* w1t_l, u16* w2t_h, u16* w2t_l,
    u16* wc2_h, u16* wc2_l, u16* wc3_h, u16* wc3_l)
{
  const int bid = blockIdx.x;
  const int tid = threadIdx.x;
  if (bid < 144) {
    prep_fr4(Wq, wqkv_h, wqkv_l, 128, 128, 49152, bid*1024 + tid*4);
  } else if (bid < 288) {
    prep_fr4(Wk, wqkv_h + 16384, wqkv_l + 16384, 128, 128, 49152,
             (bid-144)*1024 + tid*4);
  } else if (bid < 432) {
    prep_fr4(Wv, wqkv_h + 32768, wqkv_l + 32768, 128, 128, 49152,
             (bid-288)*1024 + tid*4);
  } else if (bid < 576) {
    prep_fr4(Wo, wo_h, wo_l, 128, 128, 16384, (bid-432)*1024 + tid*4);
  } else if (bid < 1152) {
    prep_fr4(W1, w1t_h, w1t_l, 128, 512, 65536, (bid-576)*1024 + tid*4);
  } else if (bid < 1728) {
    prep_fr4(W2, w2t_h, w2t_l, 512, 128, 65536, (bid-1152)*1024 + tid*4);
  } else if (bid < 1752) {
    int idx4 = (bid-1728)*1024 + tid*4;
    float4 v4 = *(const float4*)&c2w[idx4];
    float vv[4] = {v4.x, v4.y, v4.z, v4.w};
    #pragma unroll
    for (int j = 0; j < 4; j++) {
      int idx = idx4 + j;
      int c2 = idx / 384;
      int rem = idx - c2*384;
      int c1 = rem / 12;
      int kw = rem - c1*12;
      u16 h, l; splitbf(vv[j], h, l);
      size_t o = (size_t)((((c2 >> 4)*12 + kw) << 9))
               + (((c1 >> 3) << 4) + (c2 & 15))*8 + (c1 & 7);
      wc2_h[o] = h; wc2_l[o] = l;
    }
  } else {
    int idx4 = (bid-1752)*1024 + tid*4;
    float4 v4 = *(const float4*)&c3w[idx4];
    float vv[4] = {v4.x, v4.y, v4.z, v4.w};
    #pragma unroll
    for (int j = 0; j < 4; j++) {
      int idx = idx4 + j;
      int c3 = idx / 1152;
      int rem = idx - c3*1152;
      int c2 = rem / 18;
      int khkw = rem - c2*18;
      u16 h, l; splitbf(vv[j], h, l);
      int s = khkw*2 + (c2 >> 5);
      int c = c2 & 31;
      size_t o = (size_t)((((c3 >> 4)*36 + s) << 9))
               + (((c >> 3) << 4) + (c3 & 15))*8 + (c & 7);
      wc3_h[o] = h; wc3_l[o] = l;
    }
  }
}

// ---------------- layer-0 pre: LN1 + QKV (M=32, 512 thr, XCD-swizzled) -----
__global__ __launch_bounds__(512) void k_pre0(
    const float* __restrict__ hbuf,
    const float* __restrict__ sc, const float* __restrict__ bi,
    const u16* __restrict__ Qh, const u16* __restrict__ Ql,
    const float* __restrict__ bq, const float* __restrict__ bk,
    const float* __restrict__ bv, float* __restrict__ qout)
{
  __shared__ u16 sAh[32*136], sAl[32*136];
  const int tid = threadIdx.x, lane = tid & 63;
  const int m0 = xcd_swz(blockIdx.x) * 32;
  {
    const int row = tid >> 4, p = tid & 15;
    float xv[8], s = 0.f;
    const float* hp = &hbuf[(size_t)(m0 + row)*128 + p*8];
    #pragma unroll
    for (int i = 0; i < 8; i++) { xv[i] = hp[i]; s += xv[i]; }
    s += __shfl_xor(s, 1); s += __shfl_xor(s, 2);
    s += __shfl_xor(s, 4); s += __shfl_xor(s, 8);
    float mean = s * (1.f/128.f);
    float v = 0.f;
    #pragma unroll
    for (int i = 0; i < 8; i++) { float d = xv[i]-mean; v += d*d; }
    v += __shfl_xor(v, 1); v += __shfl_xor(v, 2);
    v += __shfl_xor(v, 4); v += __shfl_xor(v, 8);
    float rs = rsqrtf(v*(1.f/128.f) + 1e-5f);
    #pragma unroll
    for (int i = 0; i < 8; i++) {
      int cc = p*8 + i;
      float y = (xv[i]-mean)*rs*sc[cc] + bi[cc];
      u16 hh, ll; splitbf(y, hh, ll);
      sAh[row*136 + cc] = hh; sAl[row*136 + cc] = ll;
    }
  }
  __syncthreads();
  const int wv = tid >> 6, mq = wv >> 2, nq = wv & 3;
  const int lr = lane & 15, lg = lane >> 4, l8 = lg*8;
  for (int z = 0; z < 3; z++) {
    const u16* wh = Qh + z*16384;
    const u16* wl = Ql + z*16384;
    const float* bias = (z == 0) ? bq : (z == 1) ? bk : bv;
    float* C = qout + (size_t)z*2097152;
    f32x4 acc[2] = {};
    #pragma unroll
    for (int ks = 0; ks < 4; ks++) {
      bf16x8 ah = *(const bf16x8*)&sAh[(mq*16 + lr)*136 + ks*32 + l8];
      bf16x8 al = *(const bf16x8*)&sAl[(mq*16 + lr)*136 + ks*32 + l8];
      #pragma unroll
      for (int nf = 0; nf < 2; nf++) {
        int go = (((nq*2 + nf)*4 + ks) << 9) + (lane << 3);
        bf16x8 bh = *(const bf16x8*)(wh + go);
        bf16x8 bl = *(const bf16x8*)(wl + go);
        acc[nf] = MFMA(ah, bl, acc[nf]);
        acc[nf] = MFMA(al, bh, acc[nf]);
        acc[nf] = MFMA(ah, bh, acc[nf]);
      }
    }
    #pragma unroll
    for (int nf = 0; nf < 2; nf++) {
      int col = nq*32 + nf*16 + lr;
      float bb = bias[col];
      #pragma unroll
      for (int r = 0; r < 4; r++)
        C[(size_t)(m0 + mq*16 + lg*4 + r)*128 + col] = acc[nf][r] + bb;
    }
  }
}

// ------- FULL LAYER + (l==8) fused model tail, M=32, 512 thr, swizzled -----
__global__ __launch_bounds__(512) void k_layer(
    const float* __restrict__ qin,
    const float* __restrict__ Er,
    const u16* __restrict__ Woh, const u16* __restrict__ Wol,
    const float* __restrict__ bo,
    const float* __restrict__ sc2, const float* __restrict__ bi2,
    const u16* __restrict__ W1h, const u16* __restrict__ W1l,
    const float* __restrict__ b1,
    const u16* __restrict__ W2h, const u16* __restrict__ W2l,
    const float* __restrict__ b2,
    float* __restrict__ hbuf, float* __restrict__ ssum, int skip_init,
    int do_qkv,
    const float* __restrict__ sc1, const float* __restrict__ bi1,
    const u16* __restrict__ Qh, const u16* __restrict__ Ql,
    const float* __restrict__ bq, const float* __restrict__ bk,
    const float* __restrict__ bv, float* __restrict__ qout, int dil,
    const float* __restrict__ Wout, const float* __restrict__ bout,
    float* __restrict__ part, float* __restrict__ outf)
{
  __shared__ u16 sAh[32*136], sAl[32*136];
  __shared__ __align__(16) char ureg[17408];
  u16* hidH = (u16*)ureg;
  u16* hidL = (u16*)(ureg + 8704);
  float* dmp = (float*)ureg;
  const int tid = threadIdx.x, lane = tid & 63, wv = tid >> 6;
  const int sb = xcd_swz(blockIdx.x);
  const int m0 = sb * 32;
  const int b = m0 >> 12;
  const int t0 = m0 & 4095;
  const float* qb = qin;
  const float* kb = qin + 2097152;
  const float* vb = qin + 4194304;
  // ---- Phase A: attention (8 waves x 4 rows) -> sA  (serial, proven r16)
  for (int rr = 0; rr < 4; rr++) {
    int r = wv*4 + rr;
    int t = t0 + r;
    int bt = m0 + r;
    #pragma unroll
    for (int h = 0; h < 2; h++) {
      float qd = qb[(size_t)bt*128 + h*64 + lane];
      float s[5];
      int tpc_arr[5];
      #pragma unroll
      for (int a = 0; a < 5; a++) {
        int tp = t + (a-2)*dil;
        bool valid = (tp >= 0 && tp < T_);
        int tpc = tp < 0 ? 0 : (tp > T_-1 ? T_-1 : tp);
        tpc_arr[a] = tpc;
        float kd = kb[(size_t)(b*T_ + tpc)*128 + h*64 + lane];
        float er = Er[(h*5 + a)*64 + lane];
        float p = qd * (kd + er);
        p = wave_sum(p);
        s[a] = valid ? p * 0.125f : -1e30f;
      }
      float mx = s[0];
      #pragma unroll
      for (int a = 1; a < 5; a++) mx = fmaxf(mx, s[a]);
      float p[5], psum = 0.f;
      #pragma unroll
      for (int a = 0; a < 5; a++) { p[a] = __expf(s[a]-mx); psum += p[a]; }
      float inv = 1.f/psum;
      float o = 0.f;
      #pragma unroll
      for (int a = 0; a < 5; a++)
        o += p[a] * vb[(size_t)(b*T_ + tpc_arr[a])*128 + h*64 + lane];
      float vo = o * inv;
      u16 hh, ll; splitbf(vo, hh, ll);
      sAh[r*136 + h*64 + lane] = hh;
      sAl[r*136 + h*64 + lane] = ll;
    }
  }
  __syncthreads();
  // ---- Phase B: Wo GEMM + residual + skip-acc (h carried in registers)
  const int lr = lane & 15, lg = lane >> 4, l8 = lg*8;
  const int mq = wv >> 2, nq = wv & 3;
  float hreg[2][4];
  {
    f32x4 acc[2] = {};
    #pragma unroll
    for (int ks = 0; ks < 4; ks++) {
      bf16x8 ah = *(const bf16x8*)&sAh[(mq*16 + lr)*136 + ks*32 + l8];
      bf16x8 al = *(const bf16x8*)&sAl[(mq*16 + lr)*136 + ks*32 + l8];
      #pragma unroll
      for (int nf = 0; nf < 2; nf++) {
        int go = (((nq*2 + nf)*4 + ks) << 9) + (lane << 3);
        bf16x8 bh = *(const bf16x8*)(Woh + go);
        bf16x8 bl = *(const bf16x8*)(Wol + go);
        acc[nf] = MFMA(ah, bl, acc[nf]);
        acc[nf] = MFMA(al, bh, acc[nf]);
        acc[nf] = MFMA(ah, bh, acc[nf]);
      }
    }
    #pragma unroll
    for (int nf = 0; nf < 2; nf++) {
      int col = nq*32 + nf*16 + lr;
      float bb = bo[col];
      #pragma unroll
      for (int r = 0; r < 4; r++) {
        int row = mq*16 + lg*4 + r;
        size_t o = (size_t)(m0 + row)*128 + col;
        float val = acc[nf][r] + bb;
        if (skip_init) ssum[o] = val; else ssum[o] += val;
        float hn = hbuf[o] + val;
        hreg[nf][r] = hn;
        dmp[row*132 + col] = hn;
      }
    }
  }
  __syncthreads();
  // ---- Phase C: LN2 -> sA
  {
    const int row = tid >> 4, p = tid & 15;
    float xv[8], s = 0.f;
    const float* dp = &dmp[row*132 + p*8];
    #pragma unroll
    for (int i = 0; i < 8; i++) { xv[i] = dp[i]; s += xv[i]; }
    s += __shfl_xor(s, 1); s += __shfl_xor(s, 2);
    s += __shfl_xor(s, 4); s += __shfl_xor(s, 8);
    float mean = s * (1.f/128.f);
    float v = 0.f;
    #pragma unroll
    for (int i = 0; i < 8; i++) { float d = xv[i]-mean; v += d*d; }
    v += __shfl_xor(v, 1); v += __shfl_xor(v, 2);
    v += __shfl_xor(v, 4); v += __shfl_xor(v, 8);
    float rs = rsqrtf(v*(1.f/128.f) + 1e-5f);
    #pragma unroll
    for (int i = 0; i < 8; i++) {
      int cc = p*8 + i;
      float y = (xv[i]-mean)*rs*sc2[cc] + bi2[cc];
      u16 hh, ll; splitbf(y, hh, ll);
      sAh[row*136 + cc] = hh; sAl[row*136 + cc] = ll;
    }
  }
  __syncthreads();
  // ---- Phase D: FFN (hid single-buffered over dmp region)
  f32x4 acc2[2] = {};
  for (int c = 0; c < 4; c++) {
    f32x4 acc1[2] = {};
    #pragma unroll
    for (int ks = 0; ks < 4; ks++) {
      bf16x8 ah = *(const bf16x8*)&sAh[(mq*16 + lr)*136 + ks*32 + l8];
      bf16x8 al = *(const bf16x8*)&sAl[(mq*16 + lr)*136 + ks*32 + l8];
      #pragma unroll
      for (int nf = 0; nf < 2; nf++) {
        int go = (((c*8 + nq*2 + nf)*4 + ks) << 9) + (lane << 3);
        bf16x8 bh = *(const bf16x8*)(W1h + go);
        bf16x8 bl = *(const bf16x8*)(W1l + go);
        acc1[nf] = MFMA(ah, bl, acc1[nf]);
        acc1[nf] = MFMA(al, bh, acc1[nf]);
        acc1[nf] = MFMA(ah, bh, acc1[nf]);
      }
    }
    __syncthreads();
    #pragma unroll
    for (int nf = 0; nf < 2; nf++) {
      int col = nq*32 + nf*16 + lr;
      float bb = b1[c*128 + col];
      #pragma unroll
      for (int r = 0; r < 4; r++) {
        int row = mq*16 + lg*4 + r;
        float hv = fmaxf(acc1[nf][r] + bb, 0.f);
        u16 hh, ll; splitbf(hv, hh, ll);
        hidH[row*136 + col] = hh;
        hidL[row*136 + col] = ll;
      }
    }
    __syncthreads();
    #pragma unroll
    for (int ks = 0; ks < 4; ks++) {
      bf16x8 ah = *(const bf16x8*)&hidH[(mq*16 + lr)*136 + ks*32 + l8];
      bf16x8 al = *(const bf16x8*)&hidL[(mq*16 + lr)*136 + ks*32 + l8];
      #pragma unroll
      for (int nf = 0; nf < 2; nf++) {
        int go = (((nq*2 + nf)*16 + c*4 + ks) << 9) + (lane << 3);
        bf16x8 bh = *(const bf16x8*)(W2h + go);
        bf16x8 bl = *(const bf16x8*)(W2l + go);
        acc2[nf] = MFMA(ah, bl, acc2[nf]);
        acc2[nf] = MFMA(al, bh, acc2[nf]);
        acc2[nf] = MFMA(ah, bh, acc2[nf]);
      }
    }
  }
  __syncthreads();
  // ---- Phase E: FFN residual from hreg -> hbuf + dmp
  #pragma unroll
  for (int nf = 0; nf < 2; nf++) {
    int col = nq*32 + nf*16 + lr;
    float bb = b2[col];
    #pragma unroll
    for (int r = 0; r < 4; r++) {
      int row = mq*16 + lg*4 + r;
      size_t o = (size_t)(m0 + row)*128 + col;
      float hn = hreg[nf][r] + acc2[nf][r] + bb;
      hbuf[o] = hn;
      dmp[row*132 + col] = hn;
    }
  }
  __syncthreads();
  if (do_qkv) {
    // ---- Phase F: LN1(next) -> sA, QKV(next) -> qout
    {
      const int row = tid >> 4, p = tid & 15;
      float xv[8], s = 0.f;
      const float* dp = &dmp[row*132 + p*8];
      #pragma unroll
      for (int i = 0; i < 8; i++) { xv[i] = dp[i]; s += xv[i]; }
      s += __shfl_xor(s, 1); s += __shfl_xor(s, 2);
      s += __shfl_xor(s, 4); s += __shfl_xor(s, 8);
      float mean = s * (1.f/128.f);
      float v = 0.f;
      #pragma unroll
      for (int i = 0; i < 8; i++) { float d = xv[i]-mean; v += d*d; }
      v += __shfl_xor(v, 1); v += __shfl_xor(v, 2);
      v += __shfl_xor(v, 4); v += __shfl_xor(v, 8);
      float rs = rsqrtf(v*(1.f/128.f) + 1e-5f);
      #pragma unroll
      for (int i = 0; i < 8; i++) {
        int cc = p*8 + i;
        float y = (xv[i]-mean)*rs*sc1[cc] + bi1[cc];
        u16 hh, ll; splitbf(y, hh, ll);
        sAh[row*136 + cc] = hh; sAl[row*136 + cc] = ll;
      }
    }
    __syncthreads();
    for (int z = 0; z < 3; z++) {
      const u16* wh = Qh + z*16384;
      const u16* wl = Ql + z*16384;
      const float* bias = (z == 0) ? bq : (z == 1) ? bk : bv;
      float* C = qout + (size_t)z*2097152;
      f32x4 acc[2] = {};
      #pragma unroll
      for (int ks = 0; ks < 4; ks++) {
        bf16x8 ah = *(const bf16x8*)&sAh[(mq*16 + lr)*136 + ks*32 + l8];
        bf16x8 al = *(const bf16x8*)&sAl[(mq*16 + lr)*136 + ks*32 + l8];
        #pragma unroll
        for (int nf = 0; nf < 2; nf++) {
          int go = (((nq*2 + nf)*4 + ks) << 9) + (lane << 3);
          bf16x8 bh = *(const bf16x8*)(wh + go);
          bf16x8 bl = *(const bf16x8*)(wl + go);
          acc[nf] = MFMA(ah, bl, acc[nf]);
          acc[nf] = MFMA(al, bh, acc[nf]);
          acc[nf] = MFMA(ah, bh, acc[nf]);
        }
      }
      #pragma unroll
      for (int nf = 0; nf < 2; nf++) {
        int col = nq*32 + nf*16 + lr;
        float bb = bias[col];
        #pragma unroll
        for (int r = 0; r < 4; r++)
          C[(size_t)(m0 + mq*16 + lg*4 + r)*128 + col] = acc[nf][r] + bb;
      }
    }
  } else {
    // ---- fused model tail (l==8): out head + skip partial
    {
      const int row = tid >> 4, p = tid & 15;
      float o0 = 0.f, o1 = 0.f;
      const float* dp = &dmp[row*132 + p*8];
      #pragma unroll
      for (int i = 0; i < 8; i++) {
        float hv = fmaxf(dp[i], 0.f);
        o0 += hv * Wout[(p*8 + i)*2];
        o1 += hv * Wout[(p*8 + i)*2 + 1];
      }
      o0 += __shfl_xor(o0, 1); o0 += __shfl_xor(o0, 2);
      o0 += __shfl_xor(o0, 4); o0 += __shfl_xor(o0, 8);
      o1 += __shfl_xor(o1, 1); o1 += __shfl_xor(o1, 2);
      o1 += __shfl_xor(o1, 4); o1 += __shfl_xor(o1, 8);
      if (p == 0) {
        outf[(size_t)(m0 + row)*2]     = o0 + bout[0];
        outf[(size_t)(m0 + row)*2 + 1] = o1 + bout[1];
      }
    }
    __syncthreads();
    {
      float* pr = dmp;
      int c = tid & 127, q = tid >> 7;
      float s = 0.f;
      #pragma unroll
      for (int r = 0; r < 8; r++)
        s += fmaxf(ssum[(size_t)(m0 + q*8 + r)*128 + c], 0.f);
      pr[q*128 + c] = s;
      __syncthreads();
      if (tid < 128)
        part[(size_t)sb*128 + tid] =
            pr[tid] + pr[128+tid] + pr[256+tid] + pr[384+tid];
    }
  }
}

// ---------------- final tail: mean + t-projection --------------------------
__global__ __launch_bounds__(512) void k_tail2(
    const float* __restrict__ part, const float* __restrict__ Wt,
    const float* __restrict__ btb, float* __restrict__ out)
{
  __shared__ float mb[512];
  const int tid = threadIdx.x;
  int b = tid >> 7, c = tid & 127;
  float s = 0.f;
  for (int j = 0; j < 128; j++)
    s += part[(size_t)(b*128 + j)*128 + c];
  mb[tid] = s * (1.f/4096.f);
  __syncthreads();
  for (int i = tid; i < 1200; i += 512) {
    int bb = i / 300, j = i - bb*300;
    float acc = btb[j];
    #pragma unroll 4
    for (int k2 = 0; k2 < 128; k2++)
      acc += mb[bb*128 + k2] * Wt[k2*300 + j];
    out[32768 + i] = acc;
  }
}

// ---------------- launcher -------------------------------------------------
extern "C" void kernel_launch(void* const* d_in, const int* in_sizes, int n_in,
                              void* d_out, int out_size, void* d_ws, size_t ws_size,
                              hipStream_t stream)
{
  const float* x    = (const float*)d_in[0];
  const float* c1w  = (const float*)d_in[1];
  const float* c1b  = (const float*)d_in[2];
  const float* c2w  = (const float*)d_in[3];
  const float* c2b  = (const float*)d_in[4];
  const float* c3w  = (const float*)d_in[5];
  const float* c3b  = (const float*)d_in[6];
  const float* ln1s = (const float*)d_in[7];
  const float* ln1b = (const float*)d_in[8];
  const float* ln2s = (const float*)d_in[9];
  const float* ln2b = (const float*)d_in[10];
  const float* Wq   = (const float*)d_in[11];
  const float* bq   = (const float*)d_in[12];
  const float* Wk   = (const float*)d_in[13];
  const float* bk   = (const float*)d_in[14];
  const float* Wv   = (const float*)d_in[15];
  const float* bv   = (const float*)d_in[16];
  const float* Wo   = (const float*)d_in[17];
  const float* bo   = (const float*)d_in[18];
  const float* Er   = (const float*)d_in[19];
  const float* W1   = (const float*)d_in[20];
  const float* b1   = (const float*)d_in[21];
  const float* W2   = (const float*)d_in[22];
  const float* b2   = (const float*)d_in[23];
  const float* Wout = (const float*)d_in[24];
  const float* bout = (const float*)d_in[25];
  const float* Wt   = (const float*)d_in[26];
  const float* bt   = (const float*)d_in[27];

  char* W = (char*)d_ws;
  u16* c2o_h = (u16*)W;
  u16* c2o_l = (u16*)(W + 20971520);
  char* RB = W + 41943040;
  float* qbuf0 = (float*)RB;                 // qkv ping (25.2 MB)
  float* qbuf1 = (float*)(RB + 25165824);    // qkv pong (25.2 MB)
  char* RC = W + 100663296;
  float* hbuf = (float*)RC;
  float* ssum = (float*)(RC + 8388608);
  u16* wqkv_h = (u16*)(RC + 16777216);
  u16* wqkv_l = wqkv_h + 442368;
  u16* wo_h   = wqkv_l + 442368;
  u16* wo_l   = wo_h + 147456;
  u16* w1t_h  = wo_l + 147456;
  u16* w1t_l  = w1t_h + 589824;
  u16* w2t_h  = w1t_l + 589824;
  u16* w2t_l  = w2t_h + 589824;
  u16* wc2_h  = w2t_l + 589824;
  u16* wc2_l  = wc2_h + 24576;
  u16* wc3_h  = wc2_l + 24576;
  u16* wc3_l  = wc3_h + 147456;
  float* part  = (float*)(wc3_l + 147456);   // 512*128 floats
  float* outf  = (float*)d_out;

  k_wprep_all<<<1896, 256, 0, stream>>>(
      Wq, Wk, Wv, Wo, W1, W2, c2w, c3w,
      wqkv_h, wqkv_l, wo_h, wo_l, w1t_h, w1t_l, w2t_h, w2t_l,
      wc2_h, wc2_l, wc3_h, wc3_l);

  k_conv12m<<<dim3(1024, B_), 256, 0, stream>>>(x, c1w, c1b, wc2_h, wc2_l, c2b,
                                                c2o_h, c2o_l);
  k_conv3m<<<dim3(256, B_), 256, 0, stream>>>(c2o_h, c2o_l, wc3_h, wc3_l, c3b, hbuf);

  k_pre0<<<512, 512, 0, stream>>>(hbuf, ln1s, ln1b,
                                  wqkv_h, wqkv_l, bq, bk, bv, qbuf0);

  for (int l = 0; l < 9; l++) {
    int ln = (l < 8) ? (l + 1) : 0;
    float* qin  = (l & 1) ? qbuf1 : qbuf0;
    float* qout = (l & 1) ? qbuf0 : qbuf1;
    k_layer<<<512, 512, 0, stream>>>(
        qin, Er + l*640,
        wo_h + l*16384, wo_l + l*16384, bo + l*128,
        ln2s + l*128, ln2b + l*128,
        w1t_h + l*65536, w1t_l + l*65536, b1 + l*512,
        w2t_h + l*65536, w2t_l + l*65536, b2 + l*128,
        hbuf, ssum, (l == 0) ? 1 : 0,
        (l < 8) ? 1 : 0,
        ln1s + ln*128, ln1b + ln*128,
        wqkv_h + ln*49152, wqkv_l + ln*49152,
        bq + ln*128, bk + ln*128, bv + ln*128, qout, 1 << l,
        Wout, bout, part, outf);
  }

  k_tail2<<<1, 512, 0, stream>>>(part, Wt, bt, outf);
}

// Round 20
// 652.543 us; speedup vs baseline: 1.0075x; 1.0075x over previous
//
#include <hip/hip_runtime.h>

#define T_ 4096
#define B_ 4

typedef unsigned short u16;
typedef __bf16 bf16x8 __attribute__((ext_vector_type(8)));
typedef float f32x4 __attribute__((ext_vector_type(4)));

__device__ inline void splitbf(float v, u16& h, u16& l) {
  __bf16 hb = (__bf16)v;
  float r = v - (float)hb;
  __bf16 lb = (__bf16)r;
  h = __builtin_bit_cast(u16, hb);
  l = __builtin_bit_cast(u16, lb);
}

#define MFMA(a,b,c) __builtin_amdgcn_mfma_f32_16x16x32_bf16((a),(b),(c),0,0,0)

// XCD-aware bijective block swizzle (512 blocks, 8 XCDs, 64 contiguous each)
__device__ inline int xcd_swz(int bid) { return (bid & 7)*64 + (bid >> 3); }

// ---- fused conv1(5x3,pad2)+pool3+relu + conv2(1x12)+pool3+relu, t=4/block
__global__ __launch_bounds__(256) void k_conv12m(
    const float* __restrict__ x, const float* __restrict__ w1,
    const float* __restrict__ b1,
    const u16* __restrict__ wh, const u16* __restrict__ wl,
    const float* __restrict__ b2,
    u16* __restrict__ oh, u16* __restrict__ ol)
{
  __shared__ float sx[8][130];
  __shared__ float w1s[480];
  __shared__ float b1s[32];
  __shared__ __align__(16) char uni[27520];   // 4 regions x 6880 B
  const int tid = threadIdx.x;
  const int t0 = blockIdx.x * 4;
  const int b = blockIdx.y;
  const float* xb = x + (size_t)b*T_*128;
  for (int i = tid; i < 1024; i += 256) {
    int r = i >> 7, c = i & 127;
    int t = t0 - 2 + r;
    sx[r][c] = (t >= 0 && t < T_) ? xb[t*128 + c] : 0.f;
  }
  for (int i = tid; i < 480; i += 256) w1s[i] = w1[i];
  if (tid < 32) b1s[tid] = b1[tid];
  for (int i = tid; i < 160; i += 256) {
    int tt = i / 40, c = i - tt*40;
    u16* shp = (u16*)(uni + tt*6880);
    shp[42*40 + c] = 0;
    shp[1720 + 42*40 + c] = 0;
  }
  __syncthreads();
  {
    const int c1 = tid & 31, tt = (tid >> 5) & 3, hf = tid >> 7;
    u16* shp = (u16*)(uni + tt*6880);
    u16* slp = shp + 1720;
    float w1r[15];
    #pragma unroll
    for (int i = 0; i < 15; i++) w1r[i] = w1s[c1*15 + i];
    float bb1 = b1s[c1];
    const int wp0 = hf*21;
    float win[5][5];
    #pragma unroll
    for (int kh = 0; kh < 5; kh++)
      #pragma unroll
      for (int j = 0; j < 5; j++)
        win[kh][j] = sx[tt+kh][wp0*3 + j];
    for (int wp = wp0; wp < wp0 + 21; wp++) {
      float s0 = 0.f, s1 = 0.f, s2 = 0.f;
      #pragma unroll
      for (int kh = 0; kh < 5; kh++) {
        float wA = w1r[kh*3], wB = w1r[kh*3+1], wC = w1r[kh*3+2];
        s0 += win[kh][0]*wA + win[kh][1]*wB + win[kh][2]*wC;
        s1 += win[kh][1]*wA + win[kh][2]*wB + win[kh][3]*wC;
        s2 += win[kh][2]*wA + win[kh][3]*wB + win[kh][4]*wC;
      }
      float v = fmaxf(fmaxf(fmaxf(s0, s1), s2) + bb1, 0.f);
      u16 hh, ll; splitbf(v, hh, ll);
      int dd = wp*40 + c1;
      shp[dd] = hh; slp[dd] = ll;
      if (wp < wp0 + 20) {
        int c0n = (wp+1)*3;
        #pragma unroll
        for (int kh = 0; kh < 5; kh++) {
          win[kh][0] = win[kh][3];
          win[kh][1] = win[kh][4];
          win[kh][2] = sx[tt+kh][c0n+2];
          win[kh][3] = sx[tt+kh][c0n+3];
          win[kh][4] = sx[tt+kh][c0n+4];
        }
      }
    }
  }
  __syncthreads();
  const int lane = tid & 63;
  const int wid = tid >> 6;
  const int lr = lane & 15;
  const int lk8 = (lane >> 4) * 8;
  const u16* shw = (const u16*)(uni + wid*6880);
  const u16* slw = shw + 1720;
  f32x4 acc[2][4] = {};
  #pragma unroll 3
  for (int kw = 0; kw < 12; kw++) {
    bf16x8 bh[4], bl[4];
    #pragma unroll
    for (int nf = 0; nf < 4; nf++) {
      int go = ((nf*12 + kw) << 9) + (lane << 3);
      bh[nf] = *(const bf16x8*)(wh + go);
      bl[nf] = *(const bf16x8*)(wl + go);
    }
    #pragma unroll
    for (int mf = 0; mf < 2; mf++) {
      int lofs = (mf*16 + lr + kw)*40 + lk8;
      bf16x8 ah = *(const bf16x8*)&shw[lofs];
      bf16x8 al = *(const bf16x8*)&slw[lofs];
      #pragma unroll
      for (int nf = 0; nf < 4; nf++) {
        acc[mf][nf] = MFMA(ah, bl[nf], acc[mf][nf]);
        acc[mf][nf] = MFMA(al, bh[nf], acc[mf][nf]);
        acc[mf][nf] = MFMA(ah, bh[nf], acc[mf][nf]);
      }
    }
  }
  asm volatile("s_waitcnt lgkmcnt(0)" ::: "memory");
  float* dmpw = (float*)(uni + wid*6880);
  const int lg = lane >> 4;
  {
    int t = t0 + wid;
    for (int half = 0; half < 2; half++) {
      #pragma unroll
      for (int mf = 0; mf < 2; mf++)
        #pragma unroll
        for (int r = 0; r < 4; r++) {
          int grow = mf*16 + lg*4 + r;
          int lrow = grow - half*15;
          if (lrow >= 0 && lrow < 15) {
            #pragma unroll
            for (int nf = 0; nf < 4; nf++)
              dmpw[lrow*66 + nf*16 + lr] = acc[mf][nf][r];
          }
        }
      asm volatile("s_waitcnt lgkmcnt(0)" ::: "memory");
      #pragma unroll
      for (int it = 0; it < 5; it++) {
        float v = fmaxf(fmaxf(dmpw[(it*3)*66 + lane], dmpw[(it*3+1)*66 + lane]),
                        dmpw[(it*3+2)*66 + lane]);
        v = fmaxf(v + b2[lane], 0.f);
        u16 hh, ll; splitbf(v, hh, ll);
        size_t o = (size_t)((b*T_ + t)*10 + half*5 + it)*64 + lane;
        oh[o] = hh; ol[o] = ll;
      }
      asm volatile("s_waitcnt lgkmcnt(0)" ::: "memory");
    }
  }
}

// ---------------- conv3 (3x6, pad_h=1) + pool3 + relu via MFMA -------------
__global__ __launch_bounds__(256) void k_conv3m(
    const u16* __restrict__ ih, const u16* __restrict__ il,
    const u16* __restrict__ wh, const u16* __restrict__ wl,
    const float* __restrict__ b3, float* __restrict__ hout)
{
  __shared__ u16 sh[18*720];
  __shared__ u16 sl[18*720];
  __shared__ float dmp[48][132];
  const int tid = threadIdx.x;
  const int t0 = (blockIdx.x & 255) * 16;
  const int b = blockIdx.y;
  for (int i = tid; i < 1440; i += 256) {
    int cg = i & 7;
    int w = (i >> 3) % 10;
    int tt = i / 80;
    int t = t0 - 1 + tt;
    int dd = tt*720 + w*72 + cg*8;
    if (t >= 0 && t < T_) {
      size_t so = (size_t)((b*T_ + t)*10 + w)*64 + cg*8;
      *(ulonglong2*)&sh[dd] = *(const ulonglong2*)&ih[so];
      *(ulonglong2*)&sl[dd] = *(const ulonglong2*)&il[so];
    } else {
      ulonglong2 z; z.x = 0; z.y = 0;
      *(ulonglong2*)&sh[dd] = z;
      *(ulonglong2*)&sl[dd] = z;
    }
  }
  __syncthreads();
  const int lane = tid & 63;
  const int wid = tid >> 6;
  const int lr = lane & 15;
  const int lk8 = (lane >> 4) * 8;
  int tlm[3], wom[3];
  #pragma unroll
  for (int mf = 0; mf < 3; mf++) {
    int r = mf*16 + lr;
    tlm[mf] = r / 3;
    wom[mf] = r - tlm[mf]*3;
  }
  f32x4 acc[3][2] = {};
  #pragma unroll 2
  for (int kh = 0; kh < 3; kh++) {
    #pragma unroll
    for (int kw = 0; kw < 6; kw++) {
      #pragma unroll
      for (int chh = 0; chh < 2; chh++) {
        int s = (kh*6 + kw)*2 + chh;
        int ch = chh*32;
        bf16x8 bh[2], bl[2];
        #pragma unroll
        for (int nfl = 0; nfl < 2; nfl++) {
          int go = (((wid*2 + nfl)*36 + s) << 9) + (lane << 3);
          bh[nfl] = *(const bf16x8*)(wh + go);
          bl[nfl] = *(const bf16x8*)(wl + go);
        }
        #pragma unroll
        for (int mf = 0; mf < 3; mf++) {
          int lofs = (tlm[mf] + kh)*720 + (wom[mf] + kw)*72 + ch + lk8;
          bf16x8 ah = *(const bf16x8*)&sh[lofs];
          bf16x8 al = *(const bf16x8*)&sl[lofs];
          #pragma unroll
          for (int nfl = 0; nfl < 2; nfl++) {
            acc[mf][nfl] = MFMA(ah, bl[nfl], acc[mf][nfl]);
            acc[mf][nfl] = MFMA(al, bh[nfl], acc[mf][nfl]);
            acc[mf][nfl] = MFMA(ah, bh[nfl], acc[mf][nfl]);
          }
        }
      }
    }
  }
  const int lg = lane >> 4;
  #pragma unroll
  for (int mf = 0; mf < 3; mf++)
    #pragma unroll
    for (int r = 0; r < 4; r++) {
      int row = mf*16 + lg*4 + r;
      #pragma unroll
      for (int nfl = 0; nfl < 2; nfl++)
        dmp[row][wid*32 + nfl*16 + lr] = acc[mf][nfl][r];
    }
  __syncthreads();
  for (int i = tid; i < 2048; i += 256) {
    int c3 = i & 127;
    int tt = i >> 7;
    float v = fmaxf(fmaxf(dmp[tt*3][c3], dmp[tt*3+1][c3]), dmp[tt*3+2][c3]);
    v = fmaxf(v + b3[c3], 0.f);
    hout[(size_t)(b*T_ + t0 + tt)*128 + c3] = v;
  }
}

__device__ inline float wave_sum(float v) {
  #pragma unroll
  for (int m = 1; m < 64; m <<= 1) v += __shfl_xor(v, m, 64);
  return v;
}

// ---------------- weight prep (single launch, block-uniform segments) ------
__device__ inline void prep_fr(const float* __restrict__ src,
                               u16* __restrict__ dh, u16* __restrict__ dl,
                               int K, int N, int matStride, int idx)
{
  int mat = idx / (K*N);
  int rem = idx - mat*(K*N);
  int k = rem / N;
  int n = rem - k*N;
  float v = src[idx];
  u16 h, l; splitbf(v, h, l);
  int nt = n >> 4, ks = k >> 5, ksub = k & 31;
  size_t o = (size_t)mat*matStride + (size_t)((nt*(K>>5) + ks) << 9)
           + (((ksub >> 3) << 4) + (n & 15))*8 + (ksub & 7);
  dh[o] = h; dl[o] = l;
}

__global__ __launch_bounds__(256) void k_wprep_all(
    const float* __restrict__ Wq, const float* __restrict__ Wk,
    const float* __restrict__ Wv, const float* __restrict__ Wo,
    const float* __restrict__ W1, const float* __restrict__ W2,
    const float* __restrict__ c2w, const float* __restrict__ c3w,
    u16* wqkv_h, u16* wqkv_l, u16* wo_h, u16* wo_l,
    u16* w1t_h, u16* w1t_l, u16* w2t_h, u16* w2t_l,
    u16* wc2_h, u16* wc2_l, u16* wc3_h, u16* wc3_l)
{
  const int bid = blockIdx.x;
  const int tid = threadIdx.x;
  if (bid < 576) {
    prep_fr(Wq, wqkv_h, wqkv_l, 128, 128, 49152, bid*256 + tid);
  } else if (bid < 1152) {
    prep_fr(Wk, wqkv_h + 16384, wqkv_l + 16384, 128, 128, 49152, (bid-576)*256 + tid);
  } else if (bid < 1728) {
    prep_fr(Wv, wqkv_h + 32768, wqkv_l + 32768, 128, 128, 49152, (bid-1152)*256 + tid);
  } else if (bid < 2304) {
    prep_fr(Wo, wo_h, wo_l, 128, 128, 16384, (bid-1728)*256 + tid);
  } else if (bid < 4608) {
    prep_fr(W1, w1t_h, w1t_l, 128, 512, 65536, (bid-2304)*256 + tid);
  } else if (bid < 6912) {
    prep_fr(W2, w2t_h, w2t_l, 512, 128, 65536, (bid-4608)*256 + tid);
  } else if (bid < 7008) {
    int idx = (bid-6912)*256 + tid;
    int c2 = idx / 384;
    int rem = idx - c2*384;
    int c1 = rem / 12;
    int kw = rem - c1*12;
    float v = c2w[idx];
    u16 h, l; splitbf(v, h, l);
    size_t o = (size_t)((((c2 >> 4)*12 + kw) << 9))
             + (((c1 >> 3) << 4) + (c2 & 15))*8 + (c1 & 7);
    wc2_h[o] = h; wc2_l[o] = l;
  } else {
    int idx = (bid-7008)*256 + tid;
    int c3 = idx / 1152;
    int rem = idx - c3*1152;
    int c2 = rem / 18;
    int khkw = rem - c2*18;
    float v = c3w[idx];
    u16 h, l; splitbf(v, h, l);
    int s = khkw*2 + (c2 >> 5);
    int c = c2 & 31;
    size_t o = (size_t)((((c3 >> 4)*36 + s) << 9))
             + (((c >> 3) << 4) + (c3 & 15))*8 + (c & 7);
    wc3_h[o] = h; wc3_l[o] = l;
  }
}

// ---------------- layer-0 pre: LN1 + QKV (M=32, 512 thr, XCD-swizzled) -----
__global__ __launch_bounds__(512) void k_pre0(
    const float* __restrict__ hbuf,
    const float* __restrict__ sc, const float* __restrict__ bi,
    const u16* __restrict__ Qh, const u16* __restrict__ Ql,
    const float* __restrict__ bq, const float* __restrict__ bk,
    const float* __restrict__ bv, float* __restrict__ qout)
{
  __shared__ u16 sAh[32*136], sAl[32*136];
  const int tid = threadIdx.x, lane = tid & 63;
  const int m0 = xcd_swz(blockIdx.x) * 32;
  {
    const int row = tid >> 4, p = tid & 15;
    float xv[8], s = 0.f;
    const float* hp = &hbuf[(size_t)(m0 + row)*128 + p*8];
    #pragma unroll
    for (int i = 0; i < 8; i++) { xv[i] = hp[i]; s += xv[i]; }
    s += __shfl_xor(s, 1); s += __shfl_xor(s, 2);
    s += __shfl_xor(s, 4); s += __shfl_xor(s, 8);
    float mean = s * (1.f/128.f);
    float v = 0.f;
    #pragma unroll
    for (int i = 0; i < 8; i++) { float d = xv[i]-mean; v += d*d; }
    v += __shfl_xor(v, 1); v += __shfl_xor(v, 2);
    v += __shfl_xor(v, 4); v += __shfl_xor(v, 8);
    float rs = rsqrtf(v*(1.f/128.f) + 1e-5f);
    #pragma unroll
    for (int i = 0; i < 8; i++) {
      int cc = p*8 + i;
      float y = (xv[i]-mean)*rs*sc[cc] + bi[cc];
      u16 hh, ll; splitbf(y, hh, ll);
      sAh[row*136 + cc] = hh; sAl[row*136 + cc] = ll;
    }
  }
  __syncthreads();
  const int wv = tid >> 6, mq = wv >> 2, nq = wv & 3;
  const int lr = lane & 15, lg = lane >> 4, l8 = lg*8;
  for (int z = 0; z < 3; z++) {
    const u16* wh = Qh + z*16384;
    const u16* wl = Ql + z*16384;
    const float* bias = (z == 0) ? bq : (z == 1) ? bk : bv;
    float* C = qout + (size_t)z*2097152;
    f32x4 acc[2] = {};
    #pragma unroll
    for (int ks = 0; ks < 4; ks++) {
      bf16x8 ah = *(const bf16x8*)&sAh[(mq*16 + lr)*136 + ks*32 + l8];
      bf16x8 al = *(const bf16x8*)&sAl[(mq*16 + lr)*136 + ks*32 + l8];
      #pragma unroll
      for (int nf = 0; nf < 2; nf++) {
        int go = (((nq*2 + nf)*4 + ks) << 9) + (lane << 3);
        bf16x8 bh = *(const bf16x8*)(wh + go);
        bf16x8 bl = *(const bf16x8*)(wl + go);
        acc[nf] = MFMA(ah, bl, acc[nf]);
        acc[nf] = MFMA(al, bh, acc[nf]);
        acc[nf] = MFMA(ah, bh, acc[nf]);
      }
    }
    #pragma unroll
    for (int nf = 0; nf < 2; nf++) {
      int col = nq*32 + nf*16 + lr;
      float bb = bias[col];
      #pragma unroll
      for (int r = 0; r < 4; r++)
        C[(size_t)(m0 + mq*16 + lg*4 + r)*128 + col] = acc[nf][r] + bb;
    }
  }
}

// ------- FULL LAYER + (l==8) fused model tail, M=32, 512 thr, swizzled -----
__global__ __launch_bounds__(512) void k_layer(
    const float* __restrict__ qin,
    const float* __restrict__ Er,
    const u16* __restrict__ Woh, const u16* __restrict__ Wol,
    const float* __restrict__ bo,
    const float* __restrict__ sc2, const float* __restrict__ bi2,
    const u16* __restrict__ W1h, const u16* __restrict__ W1l,
    const float* __restrict__ b1,
    const u16* __restrict__ W2h, const u16* __restrict__ W2l,
    const float* __restrict__ b2,
    float* __restrict__ hbuf, float* __restrict__ ssum, int skip_init,
    int do_qkv,
    const float* __restrict__ sc1, const float* __restrict__ bi1,
    const u16* __restrict__ Qh, const u16* __restrict__ Ql,
    const float* __restrict__ bq, const float* __restrict__ bk,
    const float* __restrict__ bv, float* __restrict__ qout, int dil,
    const float* __restrict__ Wout, const float* __restrict__ bout,
    float* __restrict__ part, float* __restrict__ outf)
{
  __shared__ u16 sAh[32*136], sAl[32*136];
  __shared__ __align__(16) char ureg[17408];
  u16* hidH = (u16*)ureg;
  u16* hidL = (u16*)(ureg + 8704);
  float* dmp = (float*)ureg;
  const int tid = threadIdx.x, lane = tid & 63, wv = tid >> 6;
  const int sb = xcd_swz(blockIdx.x);
  const int m0 = sb * 32;
  const int b = m0 >> 12;
  const int t0 = m0 & 4095;
  const float* qb = qin;
  const float* kb = qin + 2097152;
  const float* vb = qin + 4194304;
  // ---- Phase A: attention (8 waves x 4 rows) -> sA  (serial, proven r16)
  for (int rr = 0; rr < 4; rr++) {
    int r = wv*4 + rr;
    int t = t0 + r;
    int bt = m0 + r;
    #pragma unroll
    for (int h = 0; h < 2; h++) {
      float qd = qb[(size_t)bt*128 + h*64 + lane];
      float s[5];
      int tpc_arr[5];
      #pragma unroll
      for (int a = 0; a < 5; a++) {
        int tp = t + (a-2)*dil;
        bool valid = (tp >= 0 && tp < T_);
        int tpc = tp < 0 ? 0 : (tp > T_-1 ? T_-1 : tp);
        tpc_arr[a] = tpc;
        float kd = kb[(size_t)(b*T_ + tpc)*128 + h*64 + lane];
        float er = Er[(h*5 + a)*64 + lane];
        float p = qd * (kd + er);
        p = wave_sum(p);
        s[a] = valid ? p * 0.125f : -1e30f;
      }
      float mx = s[0];
      #pragma unroll
      for (int a = 1; a < 5; a++) mx = fmaxf(mx, s[a]);
      float p[5], psum = 0.f;
      #pragma unroll
      for (int a = 0; a < 5; a++) { p[a] = __expf(s[a]-mx); psum += p[a]; }
      float inv = 1.f/psum;
      float o = 0.f;
      #pragma unroll
      for (int a = 0; a < 5; a++)
        o += p[a] * vb[(size_t)(b*T_ + tpc_arr[a])*128 + h*64 + lane];
      float vo = o * inv;
      u16 hh, ll; splitbf(vo, hh, ll);
      sAh[r*136 + h*64 + lane] = hh;
      sAl[r*136 + h*64 + lane] = ll;
    }
  }
  __syncthreads();
  // ---- Phase B: Wo GEMM + residual + skip-acc (h carried in registers)
  const int lr = lane & 15, lg = lane >> 4, l8 = lg*8;
  const int mq = wv >> 2, nq = wv & 3;
  float hreg[2][4];
  {
    f32x4 acc[2] = {};
    #pragma unroll
    for (int ks = 0; ks < 4; ks++) {
      bf16x8 ah = *(const bf16x8*)&sAh[(mq*16 + lr)*136 + ks*32 + l8];
      bf16x8 al = *(const bf16x8*)&sAl[(mq*16 + lr)*136 + ks*32 + l8];
      #pragma unroll
      for (int nf = 0; nf < 2; nf++) {
        int go = (((nq*2 + nf)*4 + ks) << 9) + (lane << 3);
        bf16x8 bh = *(const bf16x8*)(Woh + go);
        bf16x8 bl = *(const bf16x8*)(Wol + go);
        acc[nf] = MFMA(ah, bl, acc[nf]);
        acc[nf] = MFMA(al, bh, acc[nf]);
        acc[nf] = MFMA(ah, bh, acc[nf]);
      }
    }
    #pragma unroll
    for (int nf = 0; nf < 2; nf++) {
      int col = nq*32 + nf*16 + lr;
      float bb = bo[col];
      #pragma unroll
      for (int r = 0; r < 4; r++) {
        int row = mq*16 + lg*4 + r;
        size_t o = (size_t)(m0 + row)*128 + col;
        float val = acc[nf][r] + bb;
        if (skip_init) ssum[o] = val; else ssum[o] += val;
        float hn = hbuf[o] + val;
        hreg[nf][r] = hn;
        dmp[row*132 + col] = hn;
      }
    }
  }
  __syncthreads();
  // ---- Phase C: LN2 -> sA
  {
    const int row = tid >> 4, p = tid & 15;
    float xv[8], s = 0.f;
    const float* dp = &dmp[row*132 + p*8];
    #pragma unroll
    for (int i = 0; i < 8; i++) { xv[i] = dp[i]; s += xv[i]; }
    s += __shfl_xor(s, 1); s += __shfl_xor(s, 2);
    s += __shfl_xor(s, 4); s += __shfl_xor(s, 8);
    float mean = s * (1.f/128.f);
    float v = 0.f;
    #pragma unroll
    for (int i = 0; i < 8; i++) { float d = xv[i]-mean; v += d*d; }
    v += __shfl_xor(v, 1); v += __shfl_xor(v, 2);
    v += __shfl_xor(v, 4); v += __shfl_xor(v, 8);
    float rs = rsqrtf(v*(1.f/128.f) + 1e-5f);
    #pragma unroll
    for (int i = 0; i < 8; i++) {
      int cc = p*8 + i;
      float y = (xv[i]-mean)*rs*sc2[cc] + bi2[cc];
      u16 hh, ll; splitbf(y, hh, ll);
      sAh[row*136 + cc] = hh; sAl[row*136 + cc] = ll;
    }
  }
  __syncthreads();
  // ---- Phase D: FFN (hid single-buffered over dmp region)
  f32x4 acc2[2] = {};
  for (int c = 0; c < 4; c++) {
    f32x4 acc1[2] = {};
    #pragma unroll
    for (int ks = 0; ks < 4; ks++) {
      bf16x8 ah = *(const bf16x8*)&sAh[(mq*16 + lr)*136 + ks*32 + l8];
      bf16x8 al = *(const bf16x8*)&sAl[(mq*16 + lr)*136 + ks*32 + l8];
      #pragma unroll
      for (int nf = 0; nf < 2; nf++) {
        int go = (((c*8 + nq*2 + nf)*4 + ks) << 9) + (lane << 3);
        bf16x8 bh = *(const bf16x8*)(W1h + go);
        bf16x8 bl = *(const bf16x8*)(W1l + go);
        acc1[nf] = MFMA(ah, bl, acc1[nf]);
        acc1[nf] = MFMA(al, bh, acc1[nf]);
        acc1[nf] = MFMA(ah, bh, acc1[nf]);
      }
    }
    __syncthreads();
    #pragma unroll
    for (int nf = 0; nf < 2; nf++) {
      int col = nq*32 + nf*16 + lr;
      float bb = b1[c*128 + col];
      #pragma unroll
      for (int r = 0; r < 4; r++) {
        int row = mq*16 + lg*4 + r;
        float hv = fmaxf(acc1[nf][r] + bb, 0.f);
        u16 hh, ll; splitbf(hv, hh, ll);
        hidH[row*136 + col] = hh;
        hidL[row*136 + col] = ll;
      }
    }
    __syncthreads();
    #pragma unroll
    for (int ks = 0; ks < 4; ks++) {
      bf16x8 ah = *(const bf16x8*)&hidH[(mq*16 + lr)*136 + ks*32 + l8];
      bf16x8 al = *(const bf16x8*)&hidL[(mq*16 + lr)*136 + ks*32 + l8];
      #pragma unroll
      for (int nf = 0; nf < 2; nf++) {
        int go = (((nq*2 + nf)*16 + c*4 + ks) << 9) + (lane << 3);
        bf16x8 bh = *(const bf16x8*)(W2h + go);
        bf16x8 bl = *(const bf16x8*)(W2l + go);
        acc2[nf] = MFMA(ah, bl, acc2[nf]);
        acc2[nf] = MFMA(al, bh, acc2[nf]);
        acc2[nf] = MFMA(ah, bh, acc2[nf]);
      }
    }
  }
  __syncthreads();
  // ---- Phase E: FFN residual from hreg -> hbuf + dmp
  #pragma unroll
  for (int nf = 0; nf < 2; nf++) {
    int col = nq*32 + nf*16 + lr;
    float bb = b2[col];
    #pragma unroll
    for (int r = 0; r < 4; r++) {
      int row = mq*16 + lg*4 + r;
      size_t o = (size_t)(m0 + row)*128 + col;
      float hn = hreg[nf][r] + acc2[nf][r] + bb;
      hbuf[o] = hn;
      dmp[row*132 + col] = hn;
    }
  }
  __syncthreads();
  if (do_qkv) {
    // ---- Phase F: LN1(next) -> sA, QKV(next) -> qout
    {
      const int row = tid >> 4, p = tid & 15;
      float xv[8], s = 0.f;
      const float* dp = &dmp[row*132 + p*8];
      #pragma unroll
      for (int i = 0; i < 8; i++) { xv[i] = dp[i]; s += xv[i]; }
      s += __shfl_xor(s, 1); s += __shfl_xor(s, 2);
      s += __shfl_xor(s, 4); s += __shfl_xor(s, 8);
      float mean = s * (1.f/128.f);
      float v = 0.f;
      #pragma unroll
      for (int i = 0; i < 8; i++) { float d = xv[i]-mean; v += d*d; }
      v += __shfl_xor(v, 1); v += __shfl_xor(v, 2);
      v += __shfl_xor(v, 4); v += __shfl_xor(v, 8);
      float rs = rsqrtf(v*(1.f/128.f) + 1e-5f);
      #pragma unroll
      for (int i = 0; i < 8; i++) {
        int cc = p*8 + i;
        float y = (xv[i]-mean)*rs*sc1[cc] + bi1[cc];
        u16 hh, ll; splitbf(y, hh, ll);
        sAh[row*136 + cc] = hh; sAl[row*136 + cc] = ll;
      }
    }
    __syncthreads();
    for (int z = 0; z < 3; z++) {
      const u16* wh = Qh + z*16384;
      const u16* wl = Ql + z*16384;
      const float* bias = (z == 0) ? bq : (z == 1) ? bk : bv;
      float* C = qout + (size_t)z*2097152;
      f32x4 acc[2] = {};
      #pragma unroll
      for (int ks = 0; ks < 4; ks++) {
        bf16x8 ah = *(const bf16x8*)&sAh[(mq*16 + lr)*136 + ks*32 + l8];
        bf16x8 al = *(const bf16x8*)&sAl[(mq*16 + lr)*136 + ks*32 + l8];
        #pragma unroll
        for (int nf = 0; nf < 2; nf++) {
          int go = (((nq*2 + nf)*4 + ks) << 9) + (lane << 3);
          bf16x8 bh = *(const bf16x8*)(wh + go);
          bf16x8 bl = *(const bf16x8*)(wl + go);
          acc[nf] = MFMA(ah, bl, acc[nf]);
          acc[nf] = MFMA(al, bh, acc[nf]);
          acc[nf] = MFMA(ah, bh, acc[nf]);
        }
      }
      #pragma unroll
      for (int nf = 0; nf < 2; nf++) {
        int col = nq*32 + nf*16 + lr;
        float bb = bias[col];
        #pragma unroll
        for (int r = 0; r < 4; r++)
          C[(size_t)(m0 + mq*16 + lg*4 + r)*128 + col] = acc[nf][r] + bb;
      }
    }
  } else {
    // ---- fused model tail (l==8): out head + skip partial
    {
      const int row = tid >> 4, p = tid & 15;
      float o0 = 0.f, o1 = 0.f;
      const float* dp = &dmp[row*132 + p*8];
      #pragma unroll
      for (int i = 0; i < 8; i++) {
        float hv = fmaxf(dp[i], 0.f);
        o0 += hv * Wout[(p*8 + i)*2];
        o1 += hv * Wout[(p*8 + i)*2 + 1];
      }
      o0 += __shfl_xor(o0, 1); o0 += __shfl_xor(o0, 2);
      o0 += __shfl_xor(o0, 4); o0 += __shfl_xor(o0, 8);
      o1 += __shfl_xor(o1, 1); o1 += __shfl_xor(o1, 2);
      o1 += __shfl_xor(o1, 4); o1 += __shfl_xor(o1, 8);
      if (p == 0) {
        outf[(size_t)(m0 + row)*2]     = o0 + bout[0];
        outf[(size_t)(m0 + row)*2 + 1] = o1 + bout[1];
      }
    }
    __syncthreads();
    {
      float* pr = dmp;
      int c = tid & 127, q = tid >> 7;
      float s = 0.f;
      #pragma unroll
      for (int r = 0; r < 8; r++)
        s += fmaxf(ssum[(size_t)(m0 + q*8 + r)*128 + c], 0.f);
      pr[q*128 + c] = s;
      __syncthreads();
      if (tid < 128)
        part[(size_t)sb*128 + tid] =
            pr[tid] + pr[128+tid] + pr[256+tid] + pr[384+tid];
    }
  }
}

// ---------------- final tail: mean + t-projection --------------------------
__global__ __launch_bounds__(512) void k_tail2(
    const float* __restrict__ part, const float* __restrict__ Wt,
    const float* __restrict__ btb, float* __restrict__ out)
{
  __shared__ float mb[512];
  const int tid = threadIdx.x;
  int b = tid >> 7, c = tid & 127;
  float s = 0.f;
  for (int j = 0; j < 128; j++)
    s += part[(size_t)(b*128 + j)*128 + c];
  mb[tid] = s * (1.f/4096.f);
  __syncthreads();
  for (int i = tid; i < 1200; i += 512) {
    int bb = i / 300, j = i - bb*300;
    float acc = btb[j];
    #pragma unroll 4
    for (int k2 = 0; k2 < 128; k2++)
      acc += mb[bb*128 + k2] * Wt[k2*300 + j];
    out[32768 + i] = acc;
  }
}

// ---------------- launcher -------------------------------------------------
extern "C" void kernel_launch(void* const* d_in, const int* in_sizes, int n_in,
                              void* d_out, int out_size, void* d_ws, size_t ws_size,
                              hipStream_t stream)
{
  const float* x    = (const float*)d_in[0];
  const float* c1w  = (const float*)d_in[1];
  const float* c1b  = (const float*)d_in[2];
  const float* c2w  = (const float*)d_in[3];
  const float* c2b  = (const float*)d_in[4];
  const float* c3w  = (const float*)d_in[5];
  const float* c3b  = (const float*)d_in[6];
  const float* ln1s = (const float*)d_in[7];
  const float* ln1b = (const float*)d_in[8];
  const float* ln2s = (const float*)d_in[9];
  const float* ln2b = (const float*)d_in[10];
  const float* Wq   = (const float*)d_in[11];
  const float* bq   = (const float*)d_in[12];
  const float* Wk   = (const float*)d_in[13];
  const float* bk   = (const float*)d_in[14];
  const float* Wv   = (const float*)d_in[15];
  const float* bv   = (const float*)d_in[16];
  const float* Wo   = (const float*)d_in[17];
  const float* bo   = (const float*)d_in[18];
  const float* Er   = (const float*)d_in[19];
  const float* W1   = (const float*)d_in[20];
  const float* b1   = (const float*)d_in[21];
  const float* W2   = (const float*)d_in[22];
  const float* b2   = (const float*)d_in[23];
  const float* Wout = (const float*)d_in[24];
  const float* bout = (const float*)d_in[25];
  const float* Wt   = (const float*)d_in[26];
  const float* bt   = (const float*)d_in[27];

  char* W = (char*)d_ws;
  u16* c2o_h = (u16*)W;
  u16* c2o_l = (u16*)(W + 20971520);
  char* RB = W + 41943040;
  float* qbuf0 = (float*)RB;                 // qkv ping (25.2 MB)
  float* qbuf1 = (float*)(RB + 25165824);    // qkv pong (25.2 MB)
  char* RC = W + 100663296;
  float* hbuf = (float*)RC;
  float* ssum = (float*)(RC + 8388608);
  u16* wqkv_h = (u16*)(RC + 16777216);
  u16* wqkv_l = wqkv_h + 442368;
  u16* wo_h   = wqkv_l + 442368;
  u16* wo_l   = wo_h + 147456;
  u16* w1t_h  = wo_l + 147456;
  u16* w1t_l  = w1t_h + 589824;
  u16* w2t_h  = w1t_l + 589824;
  u16* w2t_l  = w2t_h + 589824;
  u16* wc2_h  = w2t_l + 589824;
  u16* wc2_l  = wc2_h + 24576;
  u16* wc3_h  = wc2_l + 24576;
  u16* wc3_l  = wc3_h + 147456;
  float* part  = (float*)(wc3_l + 147456);   // 512*128 floats
  float* outf  = (float*)d_out;

  k_wprep_all<<<7584, 256, 0, stream>>>(
      Wq, Wk, Wv, Wo, W1, W2, c2w, c3w,
      wqkv_h, wqkv_l, wo_h, wo_l, w1t_h, w1t_l, w2t_h, w2t_l,
      wc2_h, wc2_l, wc3_h, wc3_l);

  k_conv12m<<<dim3(1024, B_), 256, 0, stream>>>(x, c1w, c1b, wc2_h, wc2_l, c2b,
                                                c2o_h, c2o_l);
  k_conv3m<<<dim3(256, B_), 256, 0, stream>>>(c2o_h, c2o_l, wc3_h, wc3_l, c3b, hbuf);

  k_pre0<<<512, 512, 0, stream>>>(hbuf, ln1s, ln1b,
                                  wqkv_h, wqkv_l, bq, bk, bv, qbuf0);

  for (int l = 0; l < 9; l++) {
    int ln = (l < 8) ? (l + 1) : 0;
    float* qin  = (l & 1) ? qbuf1 : qbuf0;
    float* qout = (l & 1) ? qbuf0 : qbuf1;
    k_layer<<<512, 512, 0, stream>>>(
        qin, Er + l*640,
        wo_h + l*16384, wo_l + l*16384, bo + l*128,
        ln2s + l*128, ln2b + l*128,
        w1t_h + l*65536, w1t_l + l*65536, b1 + l*512,
        w2t_h + l*65536, w2t_l + l*65536, b2 + l*128,
        hbuf, ssum, (l == 0) ? 1 : 0,
        (l < 8) ? 1 : 0,
        ln1s + ln*128, ln1b + ln*128,
        wqkv_h + ln*49152, wqkv_l + ln*49152,
        bq + ln*128, bk + ln*128, bv + ln*128, qout, 1 << l,
        Wout, bout, part, outf);
  }

  k_tail2<<<1, 512, 0, stream>>>(part, Wt, bt, outf);
}